// Round 9
// baseline (103.600 us; speedup 1.0000x reference)
//
#include <hip/hip_runtime.h>

#define BLK 128            // 4 lanes per ray -> 32 rays/block
#define RPB 32
#define STRIDE 79          // odd -> conflict-friendly
#define NZ  80

__device__ __forceinline__ float fast_rcp(float x) { return __builtin_amdgcn_rcpf(x); }

__device__ __forceinline__ void grp_gather4(float v, int gb, float o[4]) {
    o[0] = __shfl(v, gb + 0); o[1] = __shfl(v, gb + 1);
    o[2] = __shfl(v, gb + 2); o[3] = __shfl(v, gb + 3);
}

__global__ void __launch_bounds__(BLK, 4)
VolumeRenderer_16192026706363_kernel(const float* __restrict__ ros,
                                     const float* __restrict__ rds,
                                     const float* __restrict__ w_sigma,
                                     const float* __restrict__ w_feat,
                                     const float* __restrict__ u,
                                     float* __restrict__ out,
                                     int nrays)
{
    __shared__ float lds[RPB * STRIDE];       // 10,112 B
    const int tid  = threadIdx.x;
    const int gl   = tid & 3;                 // lane within 4-lane ray group
    const int rloc = tid >> 2;
    const int ray  = blockIdx.x * RPB + rloc;
    const int wl   = tid & 63;
    const int gb   = wl & ~3;                 // group base (wave lane)
    float* my = &lds[rloc * STRIDE];

    const float LOG2E  = 1.4426950408889634f;
    const float NEGL2E = -LOG2E;
    const float DIST   = 4.0f / 63.0f;
    const float K1     = -DIST * LOG2E;

    // --- early loads ---------------------------------------------------------
    const float4 uq = *reinterpret_cast<const float4*>(u + (size_t)ray * 16 + gl * 4);
    const float ro0 = ros[ray * 3 + 0], ro1 = ros[ray * 3 + 1], ro2 = ros[ray * 3 + 2];
    const float rd0 = rds[ray * 3 + 0], rd1 = rds[ray * 3 + 1], rd2 = rds[ray * 3 + 2];
    const float s0 = w_sigma[0], s1 = w_sigma[1], s2 = w_sigma[2];

    const float sgA = ro0 * s0 + ro1 * s1 + ro2 * s2;
    const float sgB = rd0 * s0 + rd1 * s1 + rd2 * s2;
    float fA[3], fB[3];
#pragma unroll
    for (int c = 0; c < 3; c++) {
        fA[c] = ro0 * w_feat[0 * 3 + c] + ro1 * w_feat[1 * 3 + c] + ro2 * w_feat[2 * 3 + c];
        fB[c] = rd0 * w_feat[0 * 3 + c] + rd1 * w_feat[1 * 3 + c] + rd2 * w_feat[2 * 3 + c];
    }

    // --- phase A: coarse transmittance; pl[] = local products ----------------
    const int base = gl * 16;
    float pl[16];
    {
        float p = 1.0f;
#pragma unroll
        for (int t = 0; t < 16; t++) {
            float zc = fmaf(DIST, (float)(base + t), 2.0f);
            float e = exp2f(fmaxf(fmaf(sgB, zc, sgA), 0.0f) * K1) + 1e-10f;
            p *= e; pl[t] = p;
        }
    }
    float Ltot = (gl == 3) ? pl[14] : pl[15];       // exclude dummy i=63
    float g4[4];
    grp_gather4(Ltot, gb, g4);
    const float Eprod = (gl == 0) ? 1.0f : (gl == 1) ? g4[0]
                      : (gl == 2) ? g4[0] * g4[1] : g4[0] * g4[1] * g4[2];

    // fold local cdf cumsum into pl[] in place (contributions i in 1..62 only)
    {
        float cs = 0.0f, prevP = 1.0f;
#pragma unroll
        for (int t = 0; t < 16; t++) {
            float cur = pl[t];
            float w = Eprod * (prevP - cur);        // T_{i-1} - T_i
            int i = base + t;
            if (i >= 1 && i <= 62) cs += w + 1e-5f;
            pl[t] = cs;
            prevP = cur;
        }
    }
    float s4[4];
    grp_gather4(pl[15], gb, s4);                    // lane sums
    const float Csum0 = (gl == 0) ? 0.0f : (gl == 1) ? s4[0]
                      : (gl == 2) ? s4[0] + s4[1] : s4[0] + s4[1] + s4[2];
    const float C1 = s4[0];                         // = cdf[15]
    const float C2 = C1 + s4[1];                    // = cdf[31]
    const float C3 = C2 + s4[2];                    // = cdf[47]
    const float S  = C3 + s4[3];                    // = cdf[62]
    const float invS = fast_rcp(S);

    // write cdf slots (unnormalized)
#pragma unroll
    for (int t = 0; t < 16; t++) {
        int i = base + t;
        if (i >= 1 && i <= 62) my[i] = Csum0 + pl[t];
    }
    if (gl == 0) my[0] = 0.0f;

    // --- phase B: 4 searches/lane; chunk preselect + 4 LDS levels ------------
    float tv[4];
#pragma unroll
    for (int q = 0; q < 4; q++) {
        float uu = (q == 0) ? uq.x : (q == 1) ? uq.y : (q == 2) ? uq.z : uq.w;
        float us = uu * S;
        int lo = ((C1 < us) ? 16 : 0) + ((C2 < us) ? 16 : 0) + ((C3 < us) ? 16 : 0);
        int hi = lo + 15;
#pragma unroll
        for (int s = 0; s < 4; s++) {
            int mid = (lo + hi) >> 1;
            bool lt = (my[mid] < us);
            lo = lt ? mid + 1 : lo;
            hi = lt ? hi : mid;
        }
        int ind = lo;
        int below = (ind - 1 > 0) ? ind - 1 : 0;
        int above = (ind < 62) ? ind : 62;
        float c0 = my[below] * invS, c1 = my[above] * invS;
        float b0 = fmaf(DIST, (float)below, 2.0f + 0.5f * DIST);
        float denom = c1 - c0;
        denom = (denom < 1e-5f) ? 1.0f : denom;
        float db = (above > below) ? DIST : 0.0f;
        tv[q] = fmaf((uu - c0) * fast_rcp(denom), db, b0);
    }

    // --- phase C: gather 16, redundant bitonic sort --------------------------
    float arr[16];
#pragma unroll
    for (int k = 0; k < 4; k++) {
        float t4[4];
        grp_gather4(tv[k], gb, t4);
#pragma unroll
        for (int s = 0; s < 4; s++) arr[s * 4 + k] = t4[s];
    }
#pragma unroll
    for (int k = 2; k <= 16; k <<= 1) {
#pragma unroll
        for (int j = k >> 1; j > 0; j >>= 1) {
#pragma unroll
            for (int i = 0; i < 16; i++) {
                int l = i ^ j;
                if (l > i) {
                    float a = arr[i], b = arr[l];
                    float mn = fminf(a, b), mx = fmaxf(a, b);
                    bool up = ((i & k) == 0);
                    arr[i] = up ? mn : mx;
                    arr[l] = up ? mx : mn;
                }
            }
        }
    }

    // --- phase D: sentinel init + disjoint rank-scatter ----------------------
#pragma unroll
    for (int t = 0; t < 20; t++) {
        int j = gl + 4 * t;
        if (j < 78) my[j] = -1.0f;
    }
#pragma unroll
    for (int q = 0; q < 4; q++) {
        int j = gl * 4 + q;
        float v = arr[j];
        float x = (v - 2.0f) * 15.75f;            // *63/4
        int L = (int)floorf(x) + 1;
        L = (L < 1) ? 1 : (L > 63 ? 63 : L);
        my[j + L - 1] = v;
    }

    // --- phase E: reconstruct z in place (sv[t] = z[sbase+t+1]) --------------
    const int sbase = 20 * gl;
    const int slen = (gl < 3) ? 20 : 18;
    float sv[20];
    float lt = 0.0f;
#pragma unroll
    for (int t = 0; t < 20; t++) {
        if (t < slen) { sv[t] = my[sbase + t]; lt += (sv[t] >= 0.0f) ? 1.0f : 0.0f; }
        else sv[t] = 6.0f;
    }
    grp_gather4(lt, gb, g4);
    float fcnt = (gl == 0) ? 0.0f : (gl == 1) ? g4[0]
               : (gl == 2) ? g4[0] + g4[1] : g4[0] + g4[1] + g4[2];
#pragma unroll
    for (int t = 0; t < 20; t++) {
        if (t < slen) {
            bool fine = (sv[t] >= 0.0f);
            float zc = fmaf(DIST, (float)(sbase + t + 1) - fcnt, 2.0f);
            sv[t] = fine ? sv[t] : zc;
            fcnt += fine ? 1.0f : 0.0f;
        }
    }
    // carry: z[20*gl] = lane (gl-1)'s sv[19]; lane0 -> 2.0
    float carry = __shfl(sv[19], gb + ((gl == 0) ? 0 : gl - 1));
    const float z0 = (gl == 0) ? 2.0f : carry;

    // --- phase F: local transmittance products -------------------------------
    float Pl[20];
    {
        float p = 1.0f, dprev = 0.0f;
#pragma unroll
        for (int t = 0; t < 20; t++) {
            float m = (t == 0) ? z0 : sv[t - 1];      // z at position sbase+t
            float d = (gl == 3 && t == 19) ? dprev : (sv[t] - m);
            float sg = fmaf(sgB, m, sgA);
            float e = exp2f(fmaxf(sg, 0.0f) * (d * NEGL2E)) + 1e-10f;
            p *= e; Pl[t] = p;
            dprev = d;
        }
    }
    grp_gather4(Pl[19], gb, g4);
    const float E2 = (gl == 0) ? 1.0f : (gl == 1) ? g4[0]
                   : (gl == 2) ? g4[0] * g4[1] : g4[0] * g4[1] * g4[2];

    // --- phase G: weights, features, accumulate, write -----------------------
    float a0 = 0.f, a1 = 0.f, a2 = 0.f, ad = 0.f;
    float* wptr = out + (size_t)nrays * 4 + (size_t)ray * NZ + sbase;
#pragma unroll
    for (int g5 = 0; g5 < 5; g5++) {
        float wq[4];
#pragma unroll
        for (int j = 0; j < 4; j++) {
            int t = 4 * g5 + j;
            float Tprev = (t == 0) ? E2 : E2 * Pl[t - 1];
            float w = Tprev - E2 * Pl[t];
            float zk = (t == 0) ? z0 : sv[t - 1];
            float e0 = exp2f(fmaf(fB[0], zk, fA[0]) * NEGL2E);
            float e1 = exp2f(fmaf(fB[1], zk, fA[1]) * NEGL2E);
            float e2 = exp2f(fmaf(fB[2], zk, fA[2]) * NEGL2E);
            a0 = fmaf(w, fast_rcp(1.0f + e0), a0);
            a1 = fmaf(w, fast_rcp(1.0f + e1), a1);
            a2 = fmaf(w, fast_rcp(1.0f + e2), a2);
            ad = fmaf(w, zk, ad);
            wq[j] = w;
        }
        *reinterpret_cast<float4*>(wptr + 4 * g5) =
            make_float4(wq[0], wq[1], wq[2], wq[3]);
    }

    // --- group reduce rgb/depth, lane 0 writes -------------------------------
    a0 += __shfl_xor(a0, 1); a0 += __shfl_xor(a0, 2);
    a1 += __shfl_xor(a1, 1); a1 += __shfl_xor(a1, 2);
    a2 += __shfl_xor(a2, 1); a2 += __shfl_xor(a2, 2);
    ad += __shfl_xor(ad, 1); ad += __shfl_xor(ad, 2);
    if (gl == 0) {
        out[(size_t)ray * 3 + 0] = a0;
        out[(size_t)ray * 3 + 1] = a1;
        out[(size_t)ray * 3 + 2] = a2;
        out[(size_t)nrays * 3 + ray] = ad;
    }
}

extern "C" void kernel_launch(void* const* d_in, const int* in_sizes, int n_in,
                              void* d_out, int out_size, void* d_ws, size_t ws_size,
                              hipStream_t stream) {
    const float* ros = (const float*)d_in[0];
    const float* rds = (const float*)d_in[1];
    const float* w_sigma = (const float*)d_in[2];
    const float* w_feat = (const float*)d_in[3];
    const float* u = (const float*)d_in[4];
    float* out = (float*)d_out;

    int nrays = in_sizes[0] / 3;          // 131072
    int grid = nrays / RPB;               // 4096 blocks of 128 threads
    VolumeRenderer_16192026706363_kernel<<<grid, BLK, 0, stream>>>(
        ros, rds, w_sigma, w_feat, u, out, nrays);
}